// Round 10
// baseline (890.830 us; speedup 1.0000x reference)
//
#include <hip/hip_runtime.h>

// SpectralMapDecomposition — MEASUREMENT ROUND (R10).
// R9 post-mortem: four structurally different kernels all land at 650+/-12 us
// (gather-dft 3-launch / phasor 3-launch / fused-nt / fused-plain). Every kernel-side
// variable is <2%. Either the timed window is dominated by fixed harness fills
// (384us poison fills visible in counters) and ours is already ~110-130us floored,
// or ours is ~266us stuck at 2.5TB/s for a shared unknown reason. Our dispatch is
// invisible in top-5 counters (everything >=380us is a fill), so: PROBE.
//
// Probe: launch the identical fused kernel 3x back-to-back (idempotent overwrite,
// stream-serialized, correctness unaffected). dur = fixed + 3*t_ours ->
// t_ours = (dur - 649.8)/2.
//   - dur ~ 870-910  => ours at write floor => declare roofline next round.
//   - dur ~ 1180     => ours = 266us, 2.4x kernel headroom exists => attack it.

#define TWO_PI_OVER_256 0.02454369260617026f
#define SR 260   // padded LDS row stride in floats: dft read banks -> uniform 2-way (free)

typedef float vfloat4 __attribute__((ext_vector_type(4)));

__global__ __launch_bounds__(256) void fused_kernel(const float* __restrict__ img,
                                                    const vfloat4* __restrict__ mask,
                                                    float* __restrict__ out) {
    const int t   = threadIdx.x;
    const int blk = blockIdx.x;

    if (blk >= 2048) {
        // ---- mask copy: 67MB, 2048 blocks x 256 threads x 8 float4 ----
        const int mb = blk - 2048;
#pragma unroll
        for (int k = 0; k < 8; ++k) {
            const size_t e = (size_t)mb * 256 + t + (size_t)k * 524288;  // 0..4194303
            const size_t b = e >> 19;                                    // 524288 f4/batch
            const size_t r = e & 524287;
            const vfloat4 v = __builtin_nontemporal_load(&mask[b * 524288 + r]);
            __builtin_nontemporal_store(v, (vfloat4*)out + b * 4718592 + 4194304 + r);
        }
        return;
    }

    // ---- fused dft+expand: block owns output channel (b, i) ----
    __shared__ float  rows[32 * SR];   // 32 img rows, padded stride
    __shared__ float2 cp[32];          // C[b, h0..h0+31, i], pre-scaled by 1/256
    const int b = blk >> 8;
    const int i = blk & 255;

    // dft lanes: xc = x-phase (0..7), hl = row within tile (0..31); x = xc + 8*x2
    const int xc = t & 7;
    const int hl = t >> 3;
    float c0, s0, cst, sst;
    __sincosf((float)((i * xc) & 255) * TWO_PI_OVER_256, &s0, &c0);   // phasor start
    __sincosf((float)((i * 8)  & 255) * TWO_PI_OVER_256, &sst, &cst); // step e^{j*2pi*8i/256}

    // expand lanes: thread owns 4 consecutive w for 1-of-4 h rows per iteration
    const int wb  = (t & 63) * 4;
    const int hl2 = t >> 6;
    float cw[4], sw[4];
#pragma unroll
    for (int j = 0; j < 4; ++j) {
        const int k = (i * (wb + j)) & 255;    // exact twiddle index
        __sincosf((float)k * TWO_PI_OVER_256, &sw[j], &cw[j]);
    }

    const float* __restrict__ imgb  = img + (size_t)b * 65536;
    float* __restrict__       obase = out + ((size_t)b * 288 + i) * 65536;

    for (int tile = 0; tile < 8; ++tile) {
        const int h0 = tile * 32;
        // stage 32 rows (32KB) as float2; reads are L2-hits after first touch
        const float2* __restrict__ src = (const float2*)(imgb + h0 * 256);
#pragma unroll
        for (int j = 0; j < 8; ++j) {
            const int idx = t + j * 256;               // 0..2047 (float2 pairs x2)
            const int rr  = idx >> 7;                  // row 0..15  (128 f2/row)
            const int c2  = idx & 127;
            *(float2*)&rows[rr * SR + 2 * c2]        = src[rr * 128 + c2];
            *(float2*)&rows[(rr + 16) * SR + 2 * c2] = src[(rr + 16) * 128 + c2];
        }
        __syncthreads();

        // per-thread partial DFT over x = xc + 8*x2 (in-register phasor, drift ~4e-6)
        float re = 0.f, im = 0.f, c = c0, s = s0;
        const float* __restrict__ rp = &rows[hl * SR + xc];
#pragma unroll
        for (int x2 = 0; x2 < 32; ++x2) {
            const float rv = rp[8 * x2];               // 2-way banked -> free
            re = fmaf(rv, c, re);
            im = fmaf(rv, s, im);                      // +sum(r*sin); negated at cp write
            const float cn = fmaf(c, cst, -s * sst);
            s = fmaf(s, cst, c * sst);
            c = cn;
        }
        // reduce the 8 x-phases (adjacent lanes) -> full C[h0+hl]
        re += __shfl_xor(re, 1); im += __shfl_xor(im, 1);
        re += __shfl_xor(re, 2); im += __shfl_xor(im, 2);
        re += __shfl_xor(re, 4); im += __shfl_xor(im, 4);
        if (xc == 0) cp[hl] = make_float2(re * (1.f / 256.f), im * (-1.f / 256.f));
        __syncthreads();

        // expand these 32 rows: 8 iters x 4KB contiguous nt stores
#pragma unroll
        for (int it2 = 0; it2 < 8; ++it2) {
            const int h = it2 * 4 + hl2;
            const float2 cv = cp[h];                   // wave-uniform -> LDS broadcast
            vfloat4 v;
            v.x = cv.x * cw[0] - cv.y * sw[0];
            v.y = cv.x * cw[1] - cv.y * sw[1];
            v.z = cv.x * cw[2] - cv.y * sw[2];
            v.w = cv.x * cw[3] - cv.y * sw[3];
            __builtin_nontemporal_store(
                v, reinterpret_cast<vfloat4*>(obase + (size_t)(h0 + h) * 256 + wb));
        }
        // rows rewrite next tile is safe: all dft reads completed before the 2nd sync;
        // cp rewrite next tile is safe: expand reads complete before next tile's 1st sync.
    }
}

extern "C" void kernel_launch(void* const* d_in, const int* in_sizes, int n_in,
                              void* d_out, int out_size, void* d_ws, size_t ws_size,
                              hipStream_t stream) {
    const float* img  = (const float*)d_in[0];   // (8,1,256,256) fp32
    const float* mask = (const float*)d_in[1];   // (8,32,256,256) fp32
    float* out = (float*)d_out;                  // (8,288,256,256) fp32

    // PROBE: 3 identical launches (idempotent). t_ours = (dur_us - 649.8) / 2.
    fused_kernel<<<4096, 256, 0, stream>>>(img, (const vfloat4*)mask, out);
    fused_kernel<<<4096, 256, 0, stream>>>(img, (const vfloat4*)mask, out);
    fused_kernel<<<4096, 256, 0, stream>>>(img, (const vfloat4*)mask, out);
}

// Round 11
// 649.968 us; speedup vs baseline: 1.3706x; 1.3706x over previous
//
#include <hip/hip_runtime.h>

// SpectralMapDecomposition, fully fused single kernel. FINAL (post-R10 probe).
//   sep[b,i,h,w] = (1/256)*( ReC[b,h,i]*cos(2*pi*i*w/256) - ImC[b,h,i]*sin(2*pi*i*w/256) )
//   C[b,h,i] = sum_x img[b,h,x] * exp(-2*pi*j*i*x/256)
//   out = concat([sep (256 ch), mask (32 ch)], axis=1) -> (8, 288, 256, 256) fp32
//
// R10 probe (3x idempotent launches): t_kernel = (890.8 - 649.8)/2 = 120.5 us for
// ~673 MB HBM traffic = 5.58 TB/s = 89% of the fill-proven 6.29 TB/s ceiling on the
// same buffer -> at the memory roofline. The remaining ~530 us of the timed window is
// fixed harness work (2.4 GB poison fills at 384 us visible in counters + restores),
// unreachable from kernel_launch. This explains why four structurally different
// kernels (R2/R4/R7/R8: gather-dft 3-launch, phasor 3-launch, fused-nt, fused-plain)
// all measured 650 +/- 12 us: the kernel component was already <= 120 us.
//
// Structure: block (b,i) stages img[b] tile in LDS (L2-resident re-reads), computes
// C[b,h,i] via in-register phasor DFT (exact resync per tile, drift ~4e-6), expands
// immediately with nt float4 stores. Mask-copy blocks ride in the same grid.

#define TWO_PI_OVER_256 0.02454369260617026f
#define SR 260   // padded LDS row stride in floats: dft read banks -> uniform 2-way (free)

typedef float vfloat4 __attribute__((ext_vector_type(4)));

__global__ __launch_bounds__(256) void fused_kernel(const float* __restrict__ img,
                                                    const vfloat4* __restrict__ mask,
                                                    float* __restrict__ out) {
    const int t   = threadIdx.x;
    const int blk = blockIdx.x;

    if (blk >= 2048) {
        // ---- mask copy: 67MB, 2048 blocks x 256 threads x 8 float4 ----
        const int mb = blk - 2048;
#pragma unroll
        for (int k = 0; k < 8; ++k) {
            const size_t e = (size_t)mb * 256 + t + (size_t)k * 524288;  // 0..4194303
            const size_t b = e >> 19;                                    // 524288 f4/batch
            const size_t r = e & 524287;
            const vfloat4 v = __builtin_nontemporal_load(&mask[b * 524288 + r]);
            __builtin_nontemporal_store(v, (vfloat4*)out + b * 4718592 + 4194304 + r);
        }
        return;
    }

    // ---- fused dft+expand: block owns output channel (b, i) ----
    __shared__ float  rows[32 * SR];   // 32 img rows, padded stride
    __shared__ float2 cp[32];          // C[b, h0..h0+31, i], pre-scaled by 1/256
    const int b = blk >> 8;
    const int i = blk & 255;

    // dft lanes: xc = x-phase (0..7), hl = row within tile (0..31); x = xc + 8*x2
    const int xc = t & 7;
    const int hl = t >> 3;
    float c0, s0, cst, sst;
    __sincosf((float)((i * xc) & 255) * TWO_PI_OVER_256, &s0, &c0);   // phasor start
    __sincosf((float)((i * 8)  & 255) * TWO_PI_OVER_256, &sst, &cst); // step e^{j*2pi*8i/256}

    // expand lanes: thread owns 4 consecutive w for 1-of-4 h rows per iteration
    const int wb  = (t & 63) * 4;
    const int hl2 = t >> 6;
    float cw[4], sw[4];
#pragma unroll
    for (int j = 0; j < 4; ++j) {
        const int k = (i * (wb + j)) & 255;    // exact twiddle index
        __sincosf((float)k * TWO_PI_OVER_256, &sw[j], &cw[j]);
    }

    const float* __restrict__ imgb  = img + (size_t)b * 65536;
    float* __restrict__       obase = out + ((size_t)b * 288 + i) * 65536;

    for (int tile = 0; tile < 8; ++tile) {
        const int h0 = tile * 32;
        // stage 32 rows (32KB) as float2; reads are L2-hits after first touch
        const float2* __restrict__ src = (const float2*)(imgb + h0 * 256);
#pragma unroll
        for (int j = 0; j < 8; ++j) {
            const int idx = t + j * 256;               // 0..2047 (float2 pairs x2)
            const int rr  = idx >> 7;                  // row 0..15  (128 f2/row)
            const int c2  = idx & 127;
            *(float2*)&rows[rr * SR + 2 * c2]        = src[rr * 128 + c2];
            *(float2*)&rows[(rr + 16) * SR + 2 * c2] = src[(rr + 16) * 128 + c2];
        }
        __syncthreads();

        // per-thread partial DFT over x = xc + 8*x2 (in-register phasor, drift ~4e-6)
        float re = 0.f, im = 0.f, c = c0, s = s0;
        const float* __restrict__ rp = &rows[hl * SR + xc];
#pragma unroll
        for (int x2 = 0; x2 < 32; ++x2) {
            const float rv = rp[8 * x2];               // 2-way banked -> free
            re = fmaf(rv, c, re);
            im = fmaf(rv, s, im);                      // +sum(r*sin); negated at cp write
            const float cn = fmaf(c, cst, -s * sst);
            s = fmaf(s, cst, c * sst);
            c = cn;
        }
        // reduce the 8 x-phases (adjacent lanes) -> full C[h0+hl]
        re += __shfl_xor(re, 1); im += __shfl_xor(im, 1);
        re += __shfl_xor(re, 2); im += __shfl_xor(im, 2);
        re += __shfl_xor(re, 4); im += __shfl_xor(im, 4);
        if (xc == 0) cp[hl] = make_float2(re * (1.f / 256.f), im * (-1.f / 256.f));
        __syncthreads();

        // expand these 32 rows: 8 iters x 4KB contiguous nt stores
#pragma unroll
        for (int it2 = 0; it2 < 8; ++it2) {
            const int h = it2 * 4 + hl2;
            const float2 cv = cp[h];                   // wave-uniform -> LDS broadcast
            vfloat4 v;
            v.x = cv.x * cw[0] - cv.y * sw[0];
            v.y = cv.x * cw[1] - cv.y * sw[1];
            v.z = cv.x * cw[2] - cv.y * sw[2];
            v.w = cv.x * cw[3] - cv.y * sw[3];
            __builtin_nontemporal_store(
                v, reinterpret_cast<vfloat4*>(obase + (size_t)(h0 + h) * 256 + wb));
        }
        // rows rewrite next tile is safe: all dft reads completed before the 2nd sync;
        // cp rewrite next tile is safe: expand reads complete before next tile's 1st sync.
    }
}

extern "C" void kernel_launch(void* const* d_in, const int* in_sizes, int n_in,
                              void* d_out, int out_size, void* d_ws, size_t ws_size,
                              hipStream_t stream) {
    const float* img  = (const float*)d_in[0];   // (8,1,256,256) fp32
    const float* mask = (const float*)d_in[1];   // (8,32,256,256) fp32
    float* out = (float*)d_out;                  // (8,288,256,256) fp32

    fused_kernel<<<4096, 256, 0, stream>>>(img, (const vfloat4*)mask, out);
}